// Round 1
// baseline (105.322 us; speedup 1.0000x reference)
//
#include <hip/hip_runtime.h>

#define C_CH 128

// ---------------- transpose [N][C][H*W] -> [N][H*W][C] ----------------
__global__ __launch_bounds__(256) void transpose_chw_hwc(
    const float* __restrict__ in, float* __restrict__ out, int C, int HW) {
  __shared__ float tile[32][33];
  int n = blockIdx.z;
  const float* src = in + (size_t)n * C * HW;
  float* dst = out + (size_t)n * C * HW;
  int hw0 = blockIdx.x * 32;
  int c0  = blockIdx.y * 32;
  #pragma unroll
  for (int i = threadIdx.y; i < 32; i += 8) {
    int c  = c0 + i;
    int hw = hw0 + threadIdx.x;
    if (c < C && hw < HW) tile[i][threadIdx.x] = src[(size_t)c * HW + hw];
  }
  __syncthreads();
  #pragma unroll
  for (int i = threadIdx.y; i < 32; i += 8) {
    int hw = hw0 + i;
    int c  = c0 + threadIdx.x;
    if (hw < HW && c < C) dst[(size_t)hw * C + c] = tile[threadIdx.x][i];
  }
}

// ---------------- bilinear tap setup (matches reference exactly) ------
struct TapW {
  int x0, x1, y0, y1;
  float wx0, wx1, wy0, wy1;
  bool vx0, vx1, vy0, vy1;
};

__device__ __forceinline__ void tap_setup(float u, float v, int H, int W, TapW& t) {
  // reference: grid = u*2-1 ; x = ((gx+1)*W - 1)*0.5
  float gx = u * 2.0f - 1.0f;
  float gy = v * 2.0f - 1.0f;
  float x = ((gx + 1.0f) * (float)W - 1.0f) * 0.5f;
  float y = ((gy + 1.0f) * (float)H - 1.0f) * 0.5f;
  float x0f = floorf(x), y0f = floorf(y);
  t.x0 = (int)x0f; t.y0 = (int)y0f;
  t.x1 = t.x0 + 1; t.y1 = t.y0 + 1;
  t.wx1 = x - x0f; t.wx0 = 1.0f - t.wx1;
  t.wy1 = y - y0f; t.wy0 = 1.0f - t.wy1;
  t.vx0 = (t.x0 >= 0) && (t.x0 < W);
  t.vx1 = (t.x1 >= 0) && (t.x1 < W);
  t.vy0 = (t.y0 >= 0) && (t.y0 < H);
  t.vy1 = (t.y1 >= 0) && (t.y1 < H);
}

// sample from transposed [N][H][W][C] layout; lane handles channels [c, c+3]
__device__ __forceinline__ void samp_hwc(const float* __restrict__ f, int nHW,
                                         int H, int W, float u, float v, int c,
                                         float4& acc) {
  TapW t; tap_setup(u, v, H, W, t);
  const float* b0 = f + (size_t)nHW * C_CH;
  {
    if (t.vx0 && t.vy0) {
      const float4 val = *reinterpret_cast<const float4*>(b0 + ((size_t)t.y0 * W + t.x0) * C_CH + c);
      float wgt = t.wx0 * t.wy0;
      acc.x += val.x * wgt; acc.y += val.y * wgt; acc.z += val.z * wgt; acc.w += val.w * wgt;
    }
    if (t.vx1 && t.vy0) {
      const float4 val = *reinterpret_cast<const float4*>(b0 + ((size_t)t.y0 * W + t.x1) * C_CH + c);
      float wgt = t.wx1 * t.wy0;
      acc.x += val.x * wgt; acc.y += val.y * wgt; acc.z += val.z * wgt; acc.w += val.w * wgt;
    }
    if (t.vx0 && t.vy1) {
      const float4 val = *reinterpret_cast<const float4*>(b0 + ((size_t)t.y1 * W + t.x0) * C_CH + c);
      float wgt = t.wx0 * t.wy1;
      acc.x += val.x * wgt; acc.y += val.y * wgt; acc.z += val.z * wgt; acc.w += val.w * wgt;
    }
    if (t.vx1 && t.vy1) {
      const float4 val = *reinterpret_cast<const float4*>(b0 + ((size_t)t.y1 * W + t.x1) * C_CH + c);
      float wgt = t.wx1 * t.wy1;
      acc.x += val.x * wgt; acc.y += val.y * wgt; acc.z += val.z * wgt; acc.w += val.w * wgt;
    }
  }
}

// sample from native [N][C][H][W] layout (fallback if ws too small)
__device__ __forceinline__ void samp_chw(const float* __restrict__ f, int n,
                                         int H, int W, float u, float v, int c,
                                         float4& acc) {
  TapW t; tap_setup(u, v, H, W, t);
  size_t HW = (size_t)H * W;
  const float* b0 = f + (size_t)n * C_CH * HW + (size_t)c * HW;
  if (t.vx0 && t.vy0) {
    size_t off = (size_t)t.y0 * W + t.x0; float wgt = t.wx0 * t.wy0;
    acc.x += b0[off] * wgt; acc.y += b0[HW + off] * wgt;
    acc.z += b0[2 * HW + off] * wgt; acc.w += b0[3 * HW + off] * wgt;
  }
  if (t.vx1 && t.vy0) {
    size_t off = (size_t)t.y0 * W + t.x1; float wgt = t.wx1 * t.wy0;
    acc.x += b0[off] * wgt; acc.y += b0[HW + off] * wgt;
    acc.z += b0[2 * HW + off] * wgt; acc.w += b0[3 * HW + off] * wgt;
  }
  if (t.vx0 && t.vy1) {
    size_t off = (size_t)t.y1 * W + t.x0; float wgt = t.wx0 * t.wy1;
    acc.x += b0[off] * wgt; acc.y += b0[HW + off] * wgt;
    acc.z += b0[2 * HW + off] * wgt; acc.w += b0[3 * HW + off] * wgt;
  }
  if (t.vx1 && t.vy1) {
    size_t off = (size_t)t.y1 * W + t.x1; float wgt = t.wx1 * t.wy1;
    acc.x += b0[off] * wgt; acc.y += b0[HW + off] * wgt;
    acc.z += b0[2 * HW + off] * wgt; acc.w += b0[3 * HW + off] * wgt;
  }
}

// ---------------- main kernel ----------------
// 32 lanes per (q,p) point: lane handles 4 consecutive channels (float4).
// 256 threads/block -> 8 points per block -> 65536/8 = 8192 blocks.
template <bool TRANS>
__global__ __launch_bounds__(256) void bev_kernel(
    const float* __restrict__ rp,   // [4][128][128][3]
    const float* __restrict__ f0,   // level0 feats (layout per TRANS)
    const float* __restrict__ f1,   // level1 feats
    const float* __restrict__ l2i,  // [6][4][4]
    float* __restrict__ out)        // [16384][4][128]
{
  int lane = threadIdx.x & 31;
  int grp  = threadIdx.x >> 5;
  int pt   = blockIdx.x * 8 + grp;    // 0..65535 == q*4 + p
  int p = pt & 3;
  int q = pt >> 2;
  int h = q >> 7;
  int w = q & 127;
  int c = lane << 2;

  const float* rpp = rp + ((size_t)((p * 128 + h) * 128 + w)) * 3;
  float X = rpp[0] * 102.4f + (-51.2f);
  float Y = rpp[1] * 102.4f + (-51.2f);
  float Z = rpp[2] * 8.0f + (-5.0f);

  float4 acc = make_float4(0.f, 0.f, 0.f, 0.f);
  float cnt = 0.0f;

  for (int n = 0; n < 6; ++n) {
    const float* M = l2i + n * 16;
    float cx = M[0] * X + M[1] * Y + M[2]  * Z + M[3];
    float cy = M[4] * X + M[5] * Y + M[6]  * Z + M[7];
    float cz = M[8] * X + M[9] * Y + M[10] * Z + M[11];
    float dz = fmaxf(cz, 1e-5f);
    float u = cx / (dz * 704.0f);
    float v = cy / (dz * 256.0f);
    bool m = (cz > 1e-5f) && (u > 0.0f) && (u < 1.0f) && (v > 0.0f) && (v < 1.0f);
    if (m) {
      cnt += 1.0f;
      if (TRANS) {
        samp_hwc(f0, n * 32 * 88, 32, 88, u, v, c, acc);
        samp_hwc(f1, n * 16 * 44, 16, 44, u, v, c, acc);
      } else {
        samp_chw(f0, n, 32, 88, u, v, c, acc);
        samp_chw(f1, n, 16, 44, u, v, c, acc);
      }
    }
  }

  float s = 0.5f / fmaxf(cnt, 1.0f);
  float4 o = make_float4(acc.x * s, acc.y * s, acc.z * s, acc.w * s);
  *reinterpret_cast<float4*>(out + (size_t)pt * C_CH + c) = o;
}

extern "C" void kernel_launch(void* const* d_in, const int* in_sizes, int n_in,
                              void* d_out, int out_size, void* d_ws, size_t ws_size,
                              hipStream_t stream) {
  const float* rp  = (const float*)d_in[0];   // 1*4*128*128*3
  const float* f0  = (const float*)d_in[1];   // 1*6*128*32*88
  const float* f1  = (const float*)d_in[2];   // 1*6*128*16*44
  const float* l2i = (const float*)d_in[3];   // 1*6*4*4
  float* out = (float*)d_out;                 // 1*16384*4*128 fp32

  const size_t n0 = (size_t)6 * 128 * 32 * 88;  // 2162688
  const size_t n1 = (size_t)6 * 128 * 16 * 44;  // 540672
  const size_t need = (n0 + n1) * sizeof(float);

  if (ws_size >= need) {
    float* f0t = (float*)d_ws;
    float* f1t = f0t + n0;
    dim3 blkT(32, 8, 1);
    transpose_chw_hwc<<<dim3(88, 4, 6), blkT, 0, stream>>>(f0, f0t, 128, 32 * 88);
    transpose_chw_hwc<<<dim3(22, 4, 6), blkT, 0, stream>>>(f1, f1t, 128, 16 * 44);
    bev_kernel<true><<<dim3(8192), dim3(256), 0, stream>>>(rp, f0t, f1t, l2i, out);
  } else {
    bev_kernel<false><<<dim3(8192), dim3(256), 0, stream>>>(rp, f0, f1, l2i, out);
  }
}

// Round 2
// 89.919 us; speedup vs baseline: 1.1713x; 1.1713x over previous
//
#include <hip/hip_runtime.h>

#define C_CH 128

// ---------------- fused transpose [N][C][H*W] -> [N][H*W][C], both levels ---
// blockIdx.x < 88 -> level0 (HW=2816), else level1 (HW=704, tile x - 88)
__global__ __launch_bounds__(256) void transpose_both(
    const float* __restrict__ f0, const float* __restrict__ f1,
    float* __restrict__ o0, float* __restrict__ o1) {
  __shared__ float tile[32][33];
  int n = blockIdx.z;
  int lev = (blockIdx.x >= 88) ? 1 : 0;
  int xt = lev ? (blockIdx.x - 88) : blockIdx.x;
  int HW = lev ? 704 : 2816;
  const float* src = (lev ? f1 : f0) + (size_t)n * C_CH * HW;
  float* dst = (lev ? o1 : o0) + (size_t)n * C_CH * HW;
  int hw0 = xt * 32;
  int c0  = blockIdx.y * 32;
  #pragma unroll
  for (int i = threadIdx.y; i < 32; i += 8) {
    int c  = c0 + i;
    int hw = hw0 + threadIdx.x;
    if (hw < HW) tile[i][threadIdx.x] = src[(size_t)c * HW + hw];
  }
  __syncthreads();
  #pragma unroll
  for (int i = threadIdx.y; i < 32; i += 8) {
    int hw = hw0 + i;
    int c  = c0 + threadIdx.x;
    if (hw < HW) dst[(size_t)hw * C_CH + c] = tile[threadIdx.x][i];
  }
}

// ---------------- main kernel: 2-phase, taps precomputed once per (pt,cam) --
__global__ __launch_bounds__(256) void bev_main(
    const float* __restrict__ rp,   // [4][128][128][3]
    const float* __restrict__ f0t,  // [6][32][88][128]
    const float* __restrict__ f1t,  // [6][16][44][128]
    const float* __restrict__ l2i,  // [6][4][4]
    float* __restrict__ out)        // [16384][4][128]
{
  __shared__ int   s_off[8][6][2][4];
  __shared__ float s_wt [8][6][2][4];
  __shared__ float s_flag[8][6];

  int tid = threadIdx.x;
  int pt0 = blockIdx.x * 8;

  // ---- Phase A: 48 threads compute projection + taps ----
  if (tid < 48) {
    int lp = tid / 6;
    int n  = tid - lp * 6;
    int pt = pt0 + lp;
    int p = pt & 3, q = pt >> 2, h = q >> 7, w = q & 127;
    const float* rpp = rp + ((size_t)((p * 128 + h) * 128 + w)) * 3;
    float X = rpp[0] * 102.4f - 51.2f;
    float Y = rpp[1] * 102.4f - 51.2f;
    float Z = rpp[2] * 8.0f - 5.0f;
    const float* M = l2i + n * 16;
    float cx = fmaf(M[0], X, fmaf(M[1], Y, fmaf(M[2],  Z, M[3])));
    float cy = fmaf(M[4], X, fmaf(M[5], Y, fmaf(M[6],  Z, M[7])));
    float cz = fmaf(M[8], X, fmaf(M[9], Y, fmaf(M[10], Z, M[11])));
    float dz = fmaxf(cz, 1e-5f);
    float u = cx / (dz * 704.0f);
    float v = cy / (dz * 256.0f);
    bool m = (cz > 1e-5f) && (u > 0.0f) && (u < 1.0f) && (v > 0.0f) && (v < 1.0f);
    s_flag[lp][n] = m ? 1.0f : 0.0f;
    if (m) {
      float gx = u * 2.0f - 1.0f;
      float gy = v * 2.0f - 1.0f;
      #pragma unroll
      for (int lev = 0; lev < 2; ++lev) {
        const int H = lev ? 16 : 32, W = lev ? 44 : 88;
        const int base = (lev ? n * 16 * 44 : n * 32 * 88) * C_CH;
        float x = ((gx + 1.0f) * (float)W - 1.0f) * 0.5f;   // matches reference
        float y = ((gy + 1.0f) * (float)H - 1.0f) * 0.5f;
        float x0f = floorf(x), y0f = floorf(y);
        int x0 = (int)x0f, y0 = (int)y0f;
        int x1 = x0 + 1, y1 = y0 + 1;
        float wx1 = x - x0f, wx0 = 1.0f - wx1;
        float wy1 = y - y0f, wy0 = 1.0f - wy1;
        float vx0 = (x0 >= 0 && x0 < W) ? 1.f : 0.f;
        float vx1 = (x1 >= 0 && x1 < W) ? 1.f : 0.f;
        float vy0 = (y0 >= 0 && y0 < H) ? 1.f : 0.f;
        float vy1 = (y1 >= 0 && y1 < H) ? 1.f : 0.f;
        int cx0 = min(max(x0, 0), W - 1), cx1 = min(max(x1, 0), W - 1);
        int cy0 = min(max(y0, 0), H - 1), cy1 = min(max(y1, 0), H - 1);
        s_off[lp][n][lev][0] = base + (cy0 * W + cx0) * C_CH;
        s_off[lp][n][lev][1] = base + (cy0 * W + cx1) * C_CH;
        s_off[lp][n][lev][2] = base + (cy1 * W + cx0) * C_CH;
        s_off[lp][n][lev][3] = base + (cy1 * W + cx1) * C_CH;
        s_wt[lp][n][lev][0] = wx0 * wy0 * vx0 * vy0;
        s_wt[lp][n][lev][1] = wx1 * wy0 * vx1 * vy0;
        s_wt[lp][n][lev][2] = wx0 * wy1 * vx0 * vy1;
        s_wt[lp][n][lev][3] = wx1 * wy1 * vx1 * vy1;
      }
    }
  }
  __syncthreads();

  // ---- Phase B: gather. 32 lanes per point, 4 channels per lane ----
  int lane = tid & 31;
  int grp  = tid >> 5;
  int c = lane << 2;
  float4 acc = make_float4(0.f, 0.f, 0.f, 0.f);
  float cnt = 0.f;
  #pragma unroll
  for (int n = 0; n < 6; ++n) {
    float flag = s_flag[grp][n];
    cnt += flag;
    if (flag != 0.0f) {
      #pragma unroll
      for (int t = 0; t < 4; ++t) {
        float4 val = *reinterpret_cast<const float4*>(f0t + s_off[grp][n][0][t] + c);
        float wgt = s_wt[grp][n][0][t];
        acc.x = fmaf(val.x, wgt, acc.x);
        acc.y = fmaf(val.y, wgt, acc.y);
        acc.z = fmaf(val.z, wgt, acc.z);
        acc.w = fmaf(val.w, wgt, acc.w);
      }
      #pragma unroll
      for (int t = 0; t < 4; ++t) {
        float4 val = *reinterpret_cast<const float4*>(f1t + s_off[grp][n][1][t] + c);
        float wgt = s_wt[grp][n][1][t];
        acc.x = fmaf(val.x, wgt, acc.x);
        acc.y = fmaf(val.y, wgt, acc.y);
        acc.z = fmaf(val.z, wgt, acc.z);
        acc.w = fmaf(val.w, wgt, acc.w);
      }
    }
  }
  float s = 0.5f / fmaxf(cnt, 1.0f);
  int pt = pt0 + grp;
  *reinterpret_cast<float4*>(out + (size_t)pt * C_CH + c) =
      make_float4(acc.x * s, acc.y * s, acc.z * s, acc.w * s);
}

// ---------------- fallback: native CHW gather (if ws too small) -------------
__global__ __launch_bounds__(256) void bev_fallback(
    const float* __restrict__ rp, const float* __restrict__ f0,
    const float* __restrict__ f1, const float* __restrict__ l2i,
    float* __restrict__ out) {
  int lane = threadIdx.x & 31;
  int grp  = threadIdx.x >> 5;
  int pt   = blockIdx.x * 8 + grp;
  int p = pt & 3, q = pt >> 2, h = q >> 7, w = q & 127;
  int c = lane << 2;
  const float* rpp = rp + ((size_t)((p * 128 + h) * 128 + w)) * 3;
  float X = rpp[0] * 102.4f - 51.2f;
  float Y = rpp[1] * 102.4f - 51.2f;
  float Z = rpp[2] * 8.0f - 5.0f;
  float4 acc = make_float4(0.f, 0.f, 0.f, 0.f);
  float cnt = 0.0f;
  for (int n = 0; n < 6; ++n) {
    const float* M = l2i + n * 16;
    float cx = M[0] * X + M[1] * Y + M[2]  * Z + M[3];
    float cy = M[4] * X + M[5] * Y + M[6]  * Z + M[7];
    float cz = M[8] * X + M[9] * Y + M[10] * Z + M[11];
    float dz = fmaxf(cz, 1e-5f);
    float u = cx / (dz * 704.0f);
    float v = cy / (dz * 256.0f);
    if (!((cz > 1e-5f) && (u > 0.f) && (u < 1.f) && (v > 0.f) && (v < 1.f))) continue;
    cnt += 1.0f;
    float gx = u * 2.0f - 1.0f, gy = v * 2.0f - 1.0f;
    for (int lev = 0; lev < 2; ++lev) {
      const int H = lev ? 16 : 32, W = lev ? 44 : 88;
      const float* f = lev ? f1 : f0;
      size_t HW = (size_t)H * W;
      const float* b0 = f + (size_t)n * C_CH * HW + (size_t)c * HW;
      float x = ((gx + 1.0f) * (float)W - 1.0f) * 0.5f;
      float y = ((gy + 1.0f) * (float)H - 1.0f) * 0.5f;
      float x0f = floorf(x), y0f = floorf(y);
      int x0 = (int)x0f, y0 = (int)y0f, x1 = x0 + 1, y1 = y0 + 1;
      float wx1 = x - x0f, wx0 = 1.0f - wx1;
      float wy1 = y - y0f, wy0 = 1.0f - wy1;
      int xs[4] = {x0, x1, x0, x1}, ys[4] = {y0, y0, y1, y1};
      float ws4[4] = {wx0 * wy0, wx1 * wy0, wx0 * wy1, wx1 * wy1};
      for (int t = 0; t < 4; ++t) {
        if (xs[t] < 0 || xs[t] >= W || ys[t] < 0 || ys[t] >= H) continue;
        size_t off = (size_t)ys[t] * W + xs[t];
        float wgt = ws4[t];
        acc.x = fmaf(b0[off], wgt, acc.x);
        acc.y = fmaf(b0[HW + off], wgt, acc.y);
        acc.z = fmaf(b0[2 * HW + off], wgt, acc.z);
        acc.w = fmaf(b0[3 * HW + off], wgt, acc.w);
      }
    }
  }
  float s = 0.5f / fmaxf(cnt, 1.0f);
  *reinterpret_cast<float4*>(out + (size_t)pt * C_CH + c) =
      make_float4(acc.x * s, acc.y * s, acc.z * s, acc.w * s);
}

extern "C" void kernel_launch(void* const* d_in, const int* in_sizes, int n_in,
                              void* d_out, int out_size, void* d_ws, size_t ws_size,
                              hipStream_t stream) {
  const float* rp  = (const float*)d_in[0];
  const float* f0  = (const float*)d_in[1];
  const float* f1  = (const float*)d_in[2];
  const float* l2i = (const float*)d_in[3];
  float* out = (float*)d_out;

  const size_t n0 = (size_t)6 * 128 * 32 * 88;
  const size_t n1 = (size_t)6 * 128 * 16 * 44;
  const size_t need = (n0 + n1) * sizeof(float);

  if (ws_size >= need) {
    float* f0t = (float*)d_ws;
    float* f1t = f0t + n0;
    transpose_both<<<dim3(110, 4, 6), dim3(32, 8, 1), 0, stream>>>(f0, f1, f0t, f1t);
    bev_main<<<dim3(8192), dim3(256), 0, stream>>>(rp, f0t, f1t, l2i, out);
  } else {
    bev_fallback<<<dim3(8192), dim3(256), 0, stream>>>(rp, f0, f1, l2i, out);
  }
}